// Round 8
// baseline (256.505 us; speedup 1.0000x reference)
//
#include <hip/hip_runtime.h>

#define N_NODES 100000
#define N_EDGES 1600000
#define IN_F   128
#define HID_F  64
#define Z_F    32
#define NBUK   782          // ceil(100000/128) buckets of 128 dst nodes
#define BCAP   3072         // bucket capacity (mean 2046, sigma ~45)
#define P1T    4096         // edges per phase1 block (8/thread at 512 threads)
#define P1_BLOCKS ((N_EDGES + P1T - 1) / P1T)   // 391
#define DEG_PAD 100352      // N_NODES padded so DEG_PAD*4 is a 256B multiple

typedef unsigned int uint32;
typedef __attribute__((ext_vector_type(8))) short bf16x8;
typedef __attribute__((ext_vector_type(4))) float f32x4;

__device__ __forceinline__ unsigned short f2bf(float f) {
    unsigned u = __float_as_uint(f);
    u = (u + 0x7FFF + ((u >> 16) & 1)) >> 16;   // RNE
    return (unsigned short)u;
}
__device__ __forceinline__ uint32 pack2bf(float lo, float hi) {
    return (uint32)f2bf(lo) | ((uint32)f2bf(hi) << 16);
}
__device__ __forceinline__ float bflo(uint32 u) { return __uint_as_float(u << 16); }
__device__ __forceinline__ float bfhi(uint32 u) { return __uint_as_float(u & 0xFFFF0000u); }

#define ACC8(u) { a0 += bflo(u.x); a1 += bfhi(u.x); a2 += bflo(u.y); a3 += bfhi(u.y); \
                  a4 += bflo(u.z); a5 += bfhi(u.z); a6 += bflo(u.w); a7 += bfhi(u.w); }
#define FMA8(r,u) { a0 = fmaf(r, bflo(u.x), a0); a1 = fmaf(r, bfhi(u.x), a1); \
                    a2 = fmaf(r, bflo(u.y), a2); a3 = fmaf(r, bfhi(u.y), a3); \
                    a4 = fmaf(r, bflo(u.z), a4); a5 = fmaf(r, bfhi(u.z), a5); \
                    a6 = fmaf(r, bflo(u.w), a6); a7 = fmaf(r, bfhi(u.w), a7); }

// ---------------- K1: phase1 || gemm1 || weights (all depend only on inputs) -----
// blocks [0,P1_BLOCKS): bucket partition + global deg atomics
// block P1_BLOCKS: weight transpose/convert (Wt2, Wth — consumed by K2/K3 only)
// blocks (P1_BLOCKS, P1_BLOCKS+NBUK]: t1u = bf16(x@W1) UNSCALED; W1 staged to LDS
// PER BLOCK (no cross-block dependency inside this launch — race-free).
__global__ __launch_bounds__(512) void k1_kernel(const int* __restrict__ ei,
                                                 int* __restrict__ gcur,
                                                 uint32* __restrict__ pairs,
                                                 int* __restrict__ deg,
                                                 const float* __restrict__ W1,
                                                 const float* __restrict__ W2,
                                                 const float* __restrict__ Wmu,
                                                 const float* __restrict__ Wlv,
                                                 unsigned short* __restrict__ Wt2,
                                                 unsigned short* __restrict__ Wth,
                                                 const float* __restrict__ x,
                                                 unsigned short* __restrict__ t1u) {
    __shared__ __align__(16) int arena[9784];   // phase1: 39.1KB; gemm1: Cs+Wt1s 35.3KB
    int tid = threadIdx.x;
    if (blockIdx.x == P1_BLOCKS) {   // weight transpose/convert block
        for (int i = tid; i < HID_F * Z_F; i += 512) {       // Wt2[n][k] = W2[k][n]
            int n = i >> 6, k = i & 63;
            Wt2[i] = f2bf(W2[k * Z_F + n]);
        }
        for (int i = tid; i < Z_F * 64; i += 512) {          // Wth[n][k]: n<32 mu, else lv
            int n = i >> 5, k = i & 31;
            Wth[i] = f2bf(n < 32 ? Wmu[k * Z_F + n] : Wlv[k * Z_F + (n - 32)]);
        }
        return;
    }
    if (blockIdx.x < P1_BLOCKS) {
        // ---------------- phase1 body (round-4 proven, + deg atomics) ----------
        int* hist  = arena;
        int* lbase = arena + NBUK;
        int* gbase = arena + 2 * NBUK;
        int* lcur  = arena + 3 * NBUK;
        int* part  = arena + 4 * NBUK;                         // 512
        uint32* stage = (uint32*)(arena + 4 * NBUK + 512);     // P1T
        unsigned short* sbid = (unsigned short*)(arena + 4 * NBUK + 512 + P1T);
        int e0 = blockIdx.x * P1T;
        int ecnt = N_EDGES - e0; if (ecnt > P1T) ecnt = P1T;
        for (int b = tid; b < NBUK; b += 512) { hist[b] = 0; lcur[b] = 0; }
        __syncthreads();
        int myd[8];
#pragma unroll
        for (int i = 0; i < 8; i++) {
            int k = tid + i * 512;
            myd[i] = (k < ecnt) ? ei[N_EDGES + e0 + k] : -1;
        }
#pragma unroll
        for (int i = 0; i < 8; i++)
            if (myd[i] >= 0) {
                atomicAdd(&hist[myd[i] >> 7], 1);
                atomicAdd(&deg[myd[i]], 1);
            }
        __syncthreads();
        int t2 = tid * 2;
        int l0 = 0, l1 = 0, s = 0;
        if (t2 + 0 < NBUK) { l0 = hist[t2 + 0]; s += l0; }
        if (t2 + 1 < NBUK) { l1 = hist[t2 + 1]; s += l1; }
        part[tid] = s;
        __syncthreads();
        for (int off = 1; off < 512; off <<= 1) {
            int add = (tid >= off) ? part[tid - off] : 0;
            __syncthreads();
            part[tid] += add;
            __syncthreads();
        }
        int run = part[tid] - s;
        if (t2 + 0 < NBUK) { lbase[t2 + 0] = run; run += l0; }
        if (t2 + 1 < NBUK) { lbase[t2 + 1] = run; }
        for (int b = tid; b < NBUK; b += 512) {
            int h = hist[b];
            gbase[b] = h ? atomicAdd(&gcur[b], h) : 0;
        }
        __syncthreads();
#pragma unroll
        for (int i = 0; i < 8; i++) {
            int k = tid + i * 512;
            if (k < ecnt) {
                int sN = ei[e0 + k];
                int d  = myd[i];
                int b = d >> 7;
                int slot = lbase[b] + atomicAdd(&lcur[b], 1);
                stage[slot] = (uint32)sN | ((uint32)(d & 127) << 17);
                sbid[slot] = (unsigned short)b;
            }
        }
        __syncthreads();
        for (int k = tid; k < ecnt; k += 512) {
            int b = sbid[k];
            int r = gbase[b] + (k - lbase[b]);
            if (r < BCAP) pairs[(size_t)b * BCAP + r] = stage[k];
        }
        return;
    }
    // ---------------- gemm1 body: t1u = bf16(x@W1), W1 staged to LDS per block --
    unsigned short* Cs   = (unsigned short*)arena;             // 128*72 shorts (4608 ints)
    unsigned short* Wt1s = (unsigned short*)(arena + 4608);    // 64 rows x 132 shorts
    // stage+transpose W1 [128][64] -> Wt1s[n][k], row stride 132 (2-way-free banks)
    for (int i = tid; i < IN_F * HID_F; i += 512) {            // coalesced W1 read
        int k = i >> 6, n = i & 63;
        Wt1s[n * 132 + k] = f2bf(W1[i]);
    }
    __syncthreads();
    int node0 = (blockIdx.x - P1_BLOCKS - 1) * 128;
    int w = tid >> 6, lane = tid & 63;
    int m = lane & 15, quad = lane >> 4;
    int row = w * 16 + m;                          // 0..127
    int node = node0 + row;
    const float* xr = x + (size_t)min(node, N_NODES - 1) * IN_F;
    f32x4 acc0 = {0.f, 0.f, 0.f, 0.f};
    f32x4 acc1 = acc0, acc2 = acc0, acc3 = acc0;
#pragma unroll
    for (int ks = 0; ks < 4; ks++) {
        int kb = ks * 32 + quad * 8;
        float4 f0 = *(const float4*)(xr + kb);
        float4 f1 = *(const float4*)(xr + kb + 4);
        union { bf16x8 v; unsigned short u[8]; } A;
        A.u[0] = f2bf(f0.x); A.u[1] = f2bf(f0.y); A.u[2] = f2bf(f0.z); A.u[3] = f2bf(f0.w);
        A.u[4] = f2bf(f1.x); A.u[5] = f2bf(f1.y); A.u[6] = f2bf(f1.z); A.u[7] = f2bf(f1.w);
        bf16x8 b0 = *(const bf16x8*)&Wt1s[(0 * 16 + m) * 132 + kb];
        bf16x8 b1 = *(const bf16x8*)&Wt1s[(1 * 16 + m) * 132 + kb];
        bf16x8 b2 = *(const bf16x8*)&Wt1s[(2 * 16 + m) * 132 + kb];
        bf16x8 b3 = *(const bf16x8*)&Wt1s[(3 * 16 + m) * 132 + kb];
        acc0 = __builtin_amdgcn_mfma_f32_16x16x32_bf16(A.v, b0, acc0, 0, 0, 0);
        acc1 = __builtin_amdgcn_mfma_f32_16x16x32_bf16(A.v, b1, acc1, 0, 0, 0);
        acc2 = __builtin_amdgcn_mfma_f32_16x16x32_bf16(A.v, b2, acc2, 0, 0, 0);
        acc3 = __builtin_amdgcn_mfma_f32_16x16x32_bf16(A.v, b3, acc3, 0, 0, 0);
    }
    int rbase = w * 16 + quad * 4;
#pragma unroll
    for (int reg = 0; reg < 4; reg++) {
        int r = rbase + reg;
        Cs[r * 72 +  0 + m] = f2bf(acc0[reg]);
        Cs[r * 72 + 16 + m] = f2bf(acc1[reg]);
        Cs[r * 72 + 32 + m] = f2bf(acc2[reg]);
        Cs[r * 72 + 48 + m] = f2bf(acc3[reg]);
    }
    __syncthreads();
#pragma unroll
    for (int it = 0; it < 4; it++) {
        int idx = it * 512 + tid;
        int r = idx >> 4, c = idx & 15;
        int nd = node0 + r;
        if (nd < N_NODES) {
            uint2 vv = *(const uint2*)&Cs[r * 72 + c * 4];
            *(uint2*)&t1u[(size_t)nd * HID_F + c * 4] = vv;
        }
    }
}

// ---------------- K2: agg1+gemm2 with IN-BLOCK CSR build (128 nodes/bucket) ------
// CSR build: hist+scan+scatter of this bucket's pairs into LDS (phase2's code).
// Gather: 8 lanes/node-group, per-edge src dinv via deg[] FMA. gemm2 -> t2s.
__global__ __launch_bounds__(512) void agg1gemm2_kernel(const unsigned short* __restrict__ t1u,
                                                        const uint32* __restrict__ pairs,
                                                        const int* __restrict__ gcur,
                                                        const int* __restrict__ deg,
                                                        const float* __restrict__ b1,
                                                        const unsigned short* __restrict__ Wt2,
                                                        unsigned short* __restrict__ t2s) {
    __shared__ __align__(16) int arena[BCAP + 128 * 72 / 2];   // lcol | h1s (30.7KB)
    __shared__ int lhist[128];
    __shared__ int lscan[128];
    __shared__ int lcur[128];
    __shared__ float dv[128];
    int* lcol = arena;
    unsigned short* h1s = (unsigned short*)(arena + BCAP);     // 128*72 shorts
    unsigned short* Cs  = (unsigned short*)arena;              // overlays lcol (9.2<=12.3KB)
    int tid = threadIdx.x;
    int b = blockIdx.x;
    int node0 = b << 7;
    int cnt = gcur[b]; if (cnt > BCAP) cnt = BCAP;
    const uint32* pb = pairs + (size_t)b * BCAP;
    if (tid < 128) { lhist[tid] = 0; lcur[tid] = 0; }
    __syncthreads();
    for (int k = tid; k < cnt; k += 512) atomicAdd(&lhist[pb[k] >> 17], 1);
    __syncthreads();
    int v = (tid < 128) ? lhist[tid] : 0;
    if (tid < 128) lscan[tid] = v;
    __syncthreads();
    for (int off = 1; off < 128; off <<= 1) {
        int add = (tid < 128 && tid >= off) ? lscan[tid - off] : 0;
        __syncthreads();
        if (tid < 128) lscan[tid] += add;
        __syncthreads();
    }
    if (tid < 128) lscan[tid] -= v;   // exclusive
    __syncthreads();
    if (tid < 128) dv[tid] = (node0 + tid < N_NODES) ? rsqrtf((float)(lhist[tid] + 1)) : 0.f;
    for (int k = tid; k < cnt; k += 512) {
        uint32 u = pb[k];
        int ld = u >> 17;
        int r = atomicAdd(&lcur[ld], 1);
        lcol[lscan[ld] + r] = (int)(u & 0x1FFFF);
    }
    __syncthreads();
    // ---- gather: 64 groups (8 waves x 8), 8 lanes/group, 2 reps ----
    int lane = tid & 63, w = tid >> 6;
    int grp = lane >> 3, fl = lane & 7;
    int gg = w * 8 + grp;                   // 0..63
    const uint4* t1q = (const uint4*)t1u;
    float4 bb0 = ((const float4*)b1)[fl * 2];
    float4 bb1 = ((const float4*)b1)[fl * 2 + 1];
#pragma unroll
    for (int rep = 0; rep < 2; rep++) {
        int li = gg + rep * 64;             // 0..127
        int node = node0 + li;
        uint4 pk = make_uint4(0u, 0u, 0u, 0u);
        if (node < N_NODES) {
            int s = lscan[li];
            int e = s + lhist[li];
            float a0 = 0.f, a1 = 0.f, a2 = 0.f, a3 = 0.f;
            float a4 = 0.f, a5 = 0.f, a6 = 0.f, a7 = 0.f;
            int p = s;
            for (; p + 3 < e; p += 4) {
                int c0 = lcol[p], c1 = lcol[p + 1], c2 = lcol[p + 2], c3 = lcol[p + 3];
                uint4 u0 = t1q[(size_t)c0 * 8 + fl];
                uint4 u1 = t1q[(size_t)c1 * 8 + fl];
                uint4 u2 = t1q[(size_t)c2 * 8 + fl];
                uint4 u3 = t1q[(size_t)c3 * 8 + fl];
                int d0 = deg[c0], d1 = deg[c1], d2 = deg[c2], d3 = deg[c3];
                float r0 = rsqrtf((float)(d0 + 1));
                float r1 = rsqrtf((float)(d1 + 1));
                float r2 = rsqrtf((float)(d2 + 1));
                float r3 = rsqrtf((float)(d3 + 1));
                FMA8(r0, u0); FMA8(r1, u1); FMA8(r2, u2); FMA8(r3, u3);
            }
            for (; p < e; p++) {
                int c = lcol[p];
                uint4 u = t1q[(size_t)c * 8 + fl];
                float r = rsqrtf((float)(deg[c] + 1));
                FMA8(r, u);
            }
            uint4 us = t1q[(size_t)node * 8 + fl];   // self (unscaled)
            float dvl = dv[li];
            float o0 = fmaxf(fmaf(dvl, fmaf(dvl, bflo(us.x), a0), bb0.x), 0.f);
            float o1 = fmaxf(fmaf(dvl, fmaf(dvl, bfhi(us.x), a1), bb0.y), 0.f);
            float o2 = fmaxf(fmaf(dvl, fmaf(dvl, bflo(us.y), a2), bb0.z), 0.f);
            float o3 = fmaxf(fmaf(dvl, fmaf(dvl, bfhi(us.y), a3), bb0.w), 0.f);
            float o4 = fmaxf(fmaf(dvl, fmaf(dvl, bflo(us.z), a4), bb1.x), 0.f);
            float o5 = fmaxf(fmaf(dvl, fmaf(dvl, bfhi(us.z), a5), bb1.y), 0.f);
            float o6 = fmaxf(fmaf(dvl, fmaf(dvl, bflo(us.w), a6), bb1.z), 0.f);
            float o7 = fmaxf(fmaf(dvl, fmaf(dvl, bfhi(us.w), a7), bb1.w), 0.f);
            pk.x = pack2bf(o0, o1);
            pk.y = pack2bf(o2, o3);
            pk.z = pack2bf(o4, o5);
            pk.w = pack2bf(o6, o7);
        }
        *(uint4*)&h1s[li * 72 + fl * 8] = pk;
    }
    __syncthreads();
    // ---- gemm2 MFMA: M=128 (8 waves x 16 rows), K=64, N=32 ----
    int m = lane & 15, quad = lane >> 4;
    int row = w * 16 + m;
    f32x4 acc0 = {0.f, 0.f, 0.f, 0.f};
    f32x4 acc1 = acc0;
#pragma unroll
    for (int ks = 0; ks < 2; ks++) {
        int kb = ks * 32 + quad * 8;
        bf16x8 a  = *(const bf16x8*)&h1s[row * 72 + kb];
        bf16x8 B0 = *(const bf16x8*)&Wt2[(0 * 16 + m) * HID_F + kb];
        bf16x8 B1 = *(const bf16x8*)&Wt2[(1 * 16 + m) * HID_F + kb];
        acc0 = __builtin_amdgcn_mfma_f32_16x16x32_bf16(a, B0, acc0, 0, 0, 0);
        acc1 = __builtin_amdgcn_mfma_f32_16x16x32_bf16(a, B1, acc1, 0, 0, 0);
    }
    int rbase = w * 16 + quad * 4;
#pragma unroll
    for (int reg = 0; reg < 4; reg++) {
        int r = rbase + reg;
        float d = dv[r];
        Cs[r * 36 +  0 + m] = f2bf(acc0[reg] * d);
        Cs[r * 36 + 16 + m] = f2bf(acc1[reg] * d);
    }
    __syncthreads();
#pragma unroll
    for (int it = 0; it < 2; it++) {
        int idx = it * 512 + tid;
        int r = idx >> 3, c = idx & 7;
        int nd = node0 + r;
        if (nd < N_NODES) {
            uint2 vv = *(const uint2*)&Cs[r * 36 + c * 4];
            *(uint2*)&t2s[(size_t)nd * Z_F + c * 4] = vv;
        }
    }
}

// ---------------- K3: agg2+heads with IN-BLOCK CSR build (128 nodes/bucket) ------
// Gather: 4 lanes/node-group, single pass (t2s prescaled). heads MFMA -> out.
__global__ __launch_bounds__(512) void agg2heads_kernel(const unsigned short* __restrict__ t2s,
                                                        const uint32* __restrict__ pairs,
                                                        const int* __restrict__ gcur,
                                                        const float* __restrict__ b2,
                                                        const unsigned short* __restrict__ Wth,
                                                        const float* __restrict__ bmu,
                                                        const float* __restrict__ blv,
                                                        float* __restrict__ out) {
    __shared__ __align__(16) int arena[BCAP + 128 * 40 / 2];   // lcol | h2s (22.5KB)
    __shared__ int lhist[128];
    __shared__ int lscan[128];
    __shared__ int lcur[128];
    __shared__ float dv[128];
    __shared__ float bias[64];
    int* lcol = arena;
    unsigned short* h2s = (unsigned short*)(arena + BCAP);     // 128*40 shorts
    float* Cf = (float*)arena;                                 // overlays lcol+h2s (17.4<=22.5KB)
    int tid = threadIdx.x;
    int b = blockIdx.x;
    int node0 = b << 7;
    int cnt = gcur[b]; if (cnt > BCAP) cnt = BCAP;
    const uint32* pb = pairs + (size_t)b * BCAP;
    if (tid < 128) { lhist[tid] = 0; lcur[tid] = 0; }
    if (tid >= 256 && tid < 288) bias[tid - 256] = bmu[tid - 256];
    if (tid >= 288 && tid < 320) bias[tid - 288 + 32] = blv[tid - 288];
    __syncthreads();
    for (int k = tid; k < cnt; k += 512) atomicAdd(&lhist[pb[k] >> 17], 1);
    __syncthreads();
    int v = (tid < 128) ? lhist[tid] : 0;
    if (tid < 128) lscan[tid] = v;
    __syncthreads();
    for (int off = 1; off < 128; off <<= 1) {
        int add = (tid < 128 && tid >= off) ? lscan[tid - off] : 0;
        __syncthreads();
        if (tid < 128) lscan[tid] += add;
        __syncthreads();
    }
    if (tid < 128) lscan[tid] -= v;   // exclusive
    __syncthreads();
    if (tid < 128) dv[tid] = (node0 + tid < N_NODES) ? rsqrtf((float)(lhist[tid] + 1)) : 0.f;
    for (int k = tid; k < cnt; k += 512) {
        uint32 u = pb[k];
        int ld = u >> 17;
        int r = atomicAdd(&lcur[ld], 1);
        lcol[lscan[ld] + r] = (int)(u & 0x1FFFF);
    }
    __syncthreads();
    // ---- gather: 128 groups (8 waves x 16), 4 lanes/group, single pass ----
    int lane = tid & 63, w = tid >> 6;
    int grp = lane >> 2, fo = lane & 3;
    int li = w * 16 + grp;                  // 0..127
    const uint4* t2q = (const uint4*)t2s;
    float4 bb0 = ((const float4*)b2)[fo * 2];
    float4 bb1 = ((const float4*)b2)[fo * 2 + 1];
    {
        int node = node0 + li;
        uint4 pk = make_uint4(0u, 0u, 0u, 0u);
        if (node < N_NODES) {
            int s = lscan[li];
            int e = s + lhist[li];
            float a0 = 0.f, a1 = 0.f, a2 = 0.f, a3 = 0.f;
            float a4 = 0.f, a5 = 0.f, a6 = 0.f, a7 = 0.f;
            int p = s;
            for (; p + 3 < e; p += 4) {
                int c0 = lcol[p], c1 = lcol[p + 1], c2 = lcol[p + 2], c3 = lcol[p + 3];
                uint4 u0 = t2q[(size_t)c0 * 4 + fo];
                uint4 u1 = t2q[(size_t)c1 * 4 + fo];
                uint4 u2 = t2q[(size_t)c2 * 4 + fo];
                uint4 u3 = t2q[(size_t)c3 * 4 + fo];
                ACC8(u0); ACC8(u1); ACC8(u2); ACC8(u3);
            }
            for (; p < e; p++) {
                uint4 u = t2q[(size_t)lcol[p] * 4 + fo];
                ACC8(u);
            }
            uint4 us = t2q[(size_t)node * 4 + fo];
            float di = dv[li];
            float o0 = di * (a0 + bflo(us.x)) + bb0.x;
            float o1 = di * (a1 + bfhi(us.x)) + bb0.y;
            float o2 = di * (a2 + bflo(us.y)) + bb0.z;
            float o3 = di * (a3 + bfhi(us.y)) + bb0.w;
            float o4 = di * (a4 + bflo(us.z)) + bb1.x;
            float o5 = di * (a5 + bfhi(us.z)) + bb1.y;
            float o6 = di * (a6 + bflo(us.w)) + bb1.z;
            float o7 = di * (a7 + bfhi(us.w)) + bb1.w;
            pk.x = pack2bf(o0, o1);
            pk.y = pack2bf(o2, o3);
            pk.z = pack2bf(o4, o5);
            pk.w = pack2bf(o6, o7);
        }
        *(uint4*)&h2s[li * 40 + fo * 8] = pk;
    }
    __syncthreads();
    // ---- heads MFMA: M=128 (8 waves x 16 rows), K=32, N=64 (mu 0-31, lv 32-63) --
    int m = lane & 15, quad = lane >> 4;
    int row = w * 16 + m;
    int kb = quad * 8;
    bf16x8 a  = *(const bf16x8*)&h2s[row * 40 + kb];
    bf16x8 B0 = *(const bf16x8*)&Wth[(0 * 16 + m) * Z_F + kb];
    bf16x8 B1 = *(const bf16x8*)&Wth[(1 * 16 + m) * Z_F + kb];
    bf16x8 B2 = *(const bf16x8*)&Wth[(2 * 16 + m) * Z_F + kb];
    bf16x8 B3 = *(const bf16x8*)&Wth[(3 * 16 + m) * Z_F + kb];
    f32x4 acc0 = {0.f, 0.f, 0.f, 0.f};
    f32x4 acc1 = acc0, acc2 = acc0, acc3 = acc0;
    acc0 = __builtin_amdgcn_mfma_f32_16x16x32_bf16(a, B0, acc0, 0, 0, 0);
    acc1 = __builtin_amdgcn_mfma_f32_16x16x32_bf16(a, B1, acc1, 0, 0, 0);
    acc2 = __builtin_amdgcn_mfma_f32_16x16x32_bf16(a, B2, acc2, 0, 0, 0);
    acc3 = __builtin_amdgcn_mfma_f32_16x16x32_bf16(a, B3, acc3, 0, 0, 0);
    __syncthreads();   // all h2s/lcol reads done; Cf may overlay arena
    float* outlv = out + (size_t)N_NODES * Z_F;
#pragma unroll
    for (int h = 0; h < 2; h++) {
        if ((w >> 2) == h) {
            int r2 = (w & 3) * 16 + quad * 4;
#pragma unroll
            for (int reg = 0; reg < 4; reg++) {
                int rr = r2 + reg;
                Cf[rr * 68 +  0 + m] = acc0[reg] + bias[ 0 + m];
                Cf[rr * 68 + 16 + m] = acc1[reg] + bias[16 + m];
                Cf[rr * 68 + 32 + m] = acc2[reg] + bias[32 + m];
                Cf[rr * 68 + 48 + m] = acc3[reg] + bias[48 + m];
            }
        }
        __syncthreads();
        {
            int r2 = tid >> 3, c = tid & 7;
            int nd = node0 + h * 64 + r2;
            if (nd < N_NODES) {
                float4 vmu = *(const float4*)&Cf[r2 * 68 + c * 4];
                float4 vlv = *(const float4*)&Cf[r2 * 68 + 32 + c * 4];
                *(float4*)&out[(size_t)nd * Z_F + c * 4] = vmu;
                *(float4*)&outlv[(size_t)nd * Z_F + c * 4] = vlv;
            }
        }
        __syncthreads();
    }
}

extern "C" void kernel_launch(void* const* d_in, const int* in_sizes, int n_in,
                              void* d_out, int out_size, void* d_ws, size_t ws_size,
                              hipStream_t stream) {
    const float* x   = (const float*)d_in[0];
    const int*   ei  = (const int*)d_in[1];
    const float* W1  = (const float*)d_in[2];
    const float* b1  = (const float*)d_in[3];
    const float* W2  = (const float*)d_in[4];
    const float* b2  = (const float*)d_in[5];
    const float* Wmu = (const float*)d_in[6];
    const float* bmu = (const float*)d_in[7];
    const float* Wlv = (const float*)d_in[8];
    const float* blv = (const float*)d_in[9];
    float* out = (float*)d_out;

    char* ws = (char*)d_ws;
    size_t off = 0;
    auto A = [&](size_t bytes) {
        size_t r = off;
        off += (bytes + 255) & ~(size_t)255;
        return r;
    };
    int*   deg  = (int*)(ws + A((size_t)DEG_PAD * 4));   // 256B-multiple; gcur contiguous
    int*   gcur = (int*)(ws + A((size_t)NBUK * 4));
    unsigned short* Wt2 = (unsigned short*)(ws + A((size_t)HID_F * Z_F * 2));
    unsigned short* Wth = (unsigned short*)(ws + A((size_t)Z_F * 64 * 2));
    uint32* pairs = (uint32*)(ws + A((size_t)NBUK * BCAP * 4));                   // 9.6 MB
    unsigned short* t1u = (unsigned short*)(ws + A((size_t)N_NODES * HID_F * 2)); // 12.8 MB
    unsigned short* t2s = (unsigned short*)(ws + A((size_t)N_NODES * Z_F * 2));   // 6.4 MB

    // zero deg + gcur in one contiguous memset
    hipMemsetAsync(deg, 0, (size_t)DEG_PAD * 4 + (size_t)NBUK * 4, stream);

    k1_kernel<<<P1_BLOCKS + 1 + NBUK, 512, 0, stream>>>(ei, gcur, pairs, deg,
                                                        W1, W2, Wmu, Wlv, Wt2, Wth,
                                                        x, t1u);
    agg1gemm2_kernel<<<NBUK, 512, 0, stream>>>(t1u, pairs, gcur, deg, b1, Wt2, t2s);
    agg2heads_kernel<<<NBUK, 512, 0, stream>>>(t2s, pairs, gcur, b2, Wth, bmu, blv, out);
}

// Round 9
// 209.910 us; speedup vs baseline: 1.2220x; 1.2220x over previous
//
#include <hip/hip_runtime.h>

#define N_NODES 100000
#define N_EDGES 1600000
#define IN_F   128
#define HID_F  64
#define Z_F    32
#define NBUK   782          // ceil(100000/128) buckets of 128 dst nodes
#define BCAP   3072         // bucket capacity (mean 2046, sigma ~45)
#define P1T    4096         // edges per phase1 block (8/thread at 512 threads)
#define P1_BLOCKS ((N_EDGES + P1T - 1) / P1T)   // 391
#define AGG_CAP 2048        // LDS col capacity per 64-node block (mean 1024, +32 sigma)
#define G1_BLOCKS ((N_NODES + 63) / 64)         // 1563

typedef unsigned int uint32;
typedef __attribute__((ext_vector_type(8))) short bf16x8;
typedef __attribute__((ext_vector_type(4))) float f32x4;

__device__ __forceinline__ unsigned short f2bf(float f) {
    unsigned u = __float_as_uint(f);
    u = (u + 0x7FFF + ((u >> 16) & 1)) >> 16;   // RNE
    return (unsigned short)u;
}
__device__ __forceinline__ uint32 pack2bf(float lo, float hi) {
    return (uint32)f2bf(lo) | ((uint32)f2bf(hi) << 16);
}
__device__ __forceinline__ float bflo(uint32 u) { return __uint_as_float(u << 16); }
__device__ __forceinline__ float bfhi(uint32 u) { return __uint_as_float(u & 0xFFFF0000u); }

#define ACC8(u) { a0 += bflo(u.x); a1 += bfhi(u.x); a2 += bflo(u.y); a3 += bfhi(u.y); \
                  a4 += bflo(u.z); a5 += bfhi(u.z); a6 += bflo(u.w); a7 += bfhi(u.w); }

// ---------------- phase 1: bucket partition (512 thr for TLP); last blk: weights --
__global__ __launch_bounds__(512) void phase1_kernel(const int* __restrict__ ei,
                                                     int* __restrict__ gcur,
                                                     uint32* __restrict__ pairs,
                                                     const float* __restrict__ W1,
                                                     const float* __restrict__ W2,
                                                     const float* __restrict__ Wmu,
                                                     const float* __restrict__ Wlv,
                                                     unsigned short* __restrict__ Wt1,
                                                     unsigned short* __restrict__ Wt2,
                                                     unsigned short* __restrict__ Wth) {
    if (blockIdx.x == P1_BLOCKS) {   // weight transpose/convert block (no graph dep)
        int t = threadIdx.x;
        for (int i = t; i < IN_F * HID_F; i += 512) {        // Wt1[n][k] = W1[k][n]
            int n = i >> 7, k = i & 127;
            Wt1[i] = f2bf(W1[k * HID_F + n]);
        }
        for (int i = t; i < HID_F * Z_F; i += 512) {         // Wt2[n][k] = W2[k][n]
            int n = i >> 6, k = i & 63;
            Wt2[i] = f2bf(W2[k * Z_F + n]);
        }
        for (int i = t; i < Z_F * 64; i += 512) {            // Wth[n][k]: n<32 mu, else lv
            int n = i >> 5, k = i & 31;
            Wth[i] = f2bf(n < 32 ? Wmu[k * Z_F + n] : Wlv[k * Z_F + (n - 32)]);
        }
        return;
    }
    __shared__ int hist[NBUK];
    __shared__ int lbase[NBUK];
    __shared__ int gbase[NBUK];
    __shared__ int lcur[NBUK];
    __shared__ uint32 stage[P1T];
    __shared__ unsigned short sbid[P1T];
    __shared__ int wsum8[8];
    int tid = threadIdx.x;
    int e0 = blockIdx.x * P1T;
    int ecnt = N_EDGES - e0; if (ecnt > P1T) ecnt = P1T;
    for (int b = tid; b < NBUK; b += 512) { hist[b] = 0; lcur[b] = 0; }
    __syncthreads();
    int myd[8];                       // dst cached in regs: read ei's dst half ONCE
#pragma unroll
    for (int i = 0; i < 8; i++) {
        int k = tid + i * 512;
        myd[i] = (k < ecnt) ? ei[N_EDGES + e0 + k] : -1;
    }
#pragma unroll
    for (int i = 0; i < 8; i++)
        if (myd[i] >= 0) atomicAdd(&hist[myd[i] >> 7], 1);
    __syncthreads();
    int t2 = tid * 2;
    int l0 = 0, l1 = 0, s = 0;
    if (t2 + 0 < NBUK) { l0 = hist[t2 + 0]; s += l0; }
    if (t2 + 1 < NBUK) { l1 = hist[t2 + 1]; s += l1; }
    // wave-shuffle inclusive scan of s across 512 threads (barrier-light)
    int lane = tid & 63, wv = tid >> 6;
    int incl = s;
#pragma unroll
    for (int off = 1; off < 64; off <<= 1) {
        int t = __shfl_up(incl, off);
        if (lane >= off) incl += t;
    }
    if (lane == 63) wsum8[wv] = incl;
    __syncthreads();
    int wbase = 0;
    for (int i = 0; i < wv; i++) wbase += wsum8[i];
    int run = wbase + incl - s;       // exclusive prefix of s
    if (t2 + 0 < NBUK) { lbase[t2 + 0] = run; run += l0; }
    if (t2 + 1 < NBUK) { lbase[t2 + 1] = run; }
    for (int b = tid; b < NBUK; b += 512) {
        int h = hist[b];
        gbase[b] = h ? atomicAdd(&gcur[b], h) : 0;
    }
    __syncthreads();
#pragma unroll
    for (int i = 0; i < 8; i++) {
        int k = tid + i * 512;
        if (k < ecnt) {
            int sN = ei[e0 + k];
            int d  = myd[i];
            int b = d >> 7;
            int slot = lbase[b] + atomicAdd(&lcur[b], 1);
            stage[slot] = (uint32)sN | ((uint32)(d & 127) << 17);
            sbid[slot] = (unsigned short)b;
        }
    }
    __syncthreads();
    for (int k = tid; k < ecnt; k += 512) {
        int b = sbid[k];
        int r = gbase[b] + (k - lbase[b]);
        if (r < BCAP) pairs[(size_t)b * BCAP + r] = stage[k];
    }
}

// ---------------- FUSED phase2 || gemm1 (both depend only on phase1) -------------
// blocks [0,NBUK): per-bucket CSR build (self-computed bucket prefix) + dinv
// blocks [NBUK, NBUK+G1_BLOCKS): gemm1 with SELF-COMPUTED dinv (bucket histogram)
__global__ __launch_bounds__(256) void p2g1_kernel(const uint32* __restrict__ pairs,
                                                   const int* __restrict__ gcur,
                                                   int* __restrict__ rowptr,
                                                   float* __restrict__ dinv,
                                                   int* __restrict__ col,
                                                   const float* __restrict__ x,
                                                   const unsigned short* __restrict__ Wt1,
                                                   unsigned short* __restrict__ t1) {
    int tid = threadIdx.x;
    if (blockIdx.x < NBUK) {
        // ---------------- phase2 body ----------------
        __shared__ int lhist[128];
        __shared__ int lscan[128];
        __shared__ int lcur[128];
        __shared__ int stage[BCAP];
        __shared__ int wsum[4];
        int b = blockIdx.x;
        int cnt_b = gcur[b];
        if (cnt_b > BCAP) cnt_b = BCAP;
        // gbase = exclusive prefix sum of gcur over [0, b) — gcur is 3KB, L2-resident
        int partial = 0;
        for (int i = tid; i < b; i += 256) partial += gcur[i];
#pragma unroll
        for (int off = 32; off > 0; off >>= 1) partial += __shfl_down(partial, off);
        if (tid < 128) { lhist[tid] = 0; lcur[tid] = 0; }
        if ((tid & 63) == 0) wsum[tid >> 6] = partial;
        __syncthreads();
        int gbase = wsum[0] + wsum[1] + wsum[2] + wsum[3];
        int node0 = b << 7;
        int nb = N_NODES - node0;
        if (nb > 128) nb = 128;
        const uint32* pb = pairs + (size_t)b * BCAP;
        for (int k = tid; k < cnt_b; k += 256) atomicAdd(&lhist[pb[k] >> 17], 1);
        __syncthreads();
        // wave-shuffle scan over the 128 counters (tid-waves 0,1; barrier-light)
        int v = (tid < 128) ? lhist[tid] : 0;
        int lane = tid & 63, wv = tid >> 6;
        int incl = v;
#pragma unroll
        for (int off = 1; off < 64; off <<= 1) {
            int t = __shfl_up(incl, off);
            if (lane >= off) incl += t;
        }
        if (wv < 2 && lane == 63) wsum[wv] = incl;   // wave totals (gbase read done)
        __syncthreads();
        if (tid < 128) lscan[tid] = incl - v + (wv ? wsum[0] : 0);  // exclusive
        __syncthreads();
        if (tid < nb) {
            rowptr[node0 + tid] = gbase + lscan[tid];
            dinv[node0 + tid] = rsqrtf((float)(lhist[tid] + 1));
        }
        if (b == NBUK - 1 && tid == 0) rowptr[N_NODES] = N_EDGES;
        for (int k = tid; k < cnt_b; k += 256) {
            uint32 u = pb[k];
            int ld = u >> 17;
            int r = atomicAdd(&lcur[ld], 1);
            stage[lscan[ld] + r] = (int)(u & 0x1FFFF);
        }
        __syncthreads();
        for (int k = tid; k < cnt_b; k += 256) col[gbase + k] = stage[k];
        return;
    }
    // ---------------- gemm1 body (self-computed dinv from pairs histogram) -------
    __shared__ unsigned short Cs[64 * 72];
    __shared__ float dv[64];
    __shared__ int h64[64];
    int g = blockIdx.x - NBUK;
    int node0 = g * 64;
    int bk = node0 >> 7, half = (node0 >> 6) & 1;
    int cnt_b = gcur[bk];
    if (cnt_b > BCAP) cnt_b = BCAP;
    if (tid < 64) h64[tid] = 0;
    __syncthreads();
    const uint32* pb = pairs + (size_t)bk * BCAP;
    for (int k = tid; k < cnt_b; k += 256) {
        int ld = pb[k] >> 17;
        if ((ld >> 6) == half) atomicAdd(&h64[ld & 63], 1);
    }
    __syncthreads();
    if (tid < 64) {
        int n = node0 + tid;
        dv[tid] = (n < N_NODES) ? rsqrtf((float)(h64[tid] + 1)) : 0.f;
    }
    __syncthreads();
    int w = tid >> 6, lane = tid & 63;
    int m = lane & 15, quad = lane >> 4;
    int row = w * 16 + m;
    int node = node0 + row;
    const float* xr = x + (size_t)min(node, N_NODES - 1) * IN_F;
    f32x4 acc0 = {0.f, 0.f, 0.f, 0.f};
    f32x4 acc1 = acc0, acc2 = acc0, acc3 = acc0;
#pragma unroll
    for (int ks = 0; ks < 4; ks++) {
        int kb = ks * 32 + quad * 8;
        float4 f0 = *(const float4*)(xr + kb);
        float4 f1 = *(const float4*)(xr + kb + 4);
        union { bf16x8 v; unsigned short u[8]; } A;
        A.u[0] = f2bf(f0.x); A.u[1] = f2bf(f0.y); A.u[2] = f2bf(f0.z); A.u[3] = f2bf(f0.w);
        A.u[4] = f2bf(f1.x); A.u[5] = f2bf(f1.y); A.u[6] = f2bf(f1.z); A.u[7] = f2bf(f1.w);
        bf16x8 b0 = *(const bf16x8*)&Wt1[(0 * 16 + m) * IN_F + kb];
        bf16x8 b1 = *(const bf16x8*)&Wt1[(1 * 16 + m) * IN_F + kb];
        bf16x8 b2 = *(const bf16x8*)&Wt1[(2 * 16 + m) * IN_F + kb];
        bf16x8 b3 = *(const bf16x8*)&Wt1[(3 * 16 + m) * IN_F + kb];
        acc0 = __builtin_amdgcn_mfma_f32_16x16x32_bf16(A.v, b0, acc0, 0, 0, 0);
        acc1 = __builtin_amdgcn_mfma_f32_16x16x32_bf16(A.v, b1, acc1, 0, 0, 0);
        acc2 = __builtin_amdgcn_mfma_f32_16x16x32_bf16(A.v, b2, acc2, 0, 0, 0);
        acc3 = __builtin_amdgcn_mfma_f32_16x16x32_bf16(A.v, b3, acc3, 0, 0, 0);
    }
    int rbase = w * 16 + quad * 4;
#pragma unroll
    for (int reg = 0; reg < 4; reg++) {
        int r = rbase + reg;
        float d = dv[r];
        Cs[r * 72 +  0 + m] = f2bf(acc0[reg] * d);
        Cs[r * 72 + 16 + m] = f2bf(acc1[reg] * d);
        Cs[r * 72 + 32 + m] = f2bf(acc2[reg] * d);
        Cs[r * 72 + 48 + m] = f2bf(acc3[reg] * d);
    }
    __syncthreads();
#pragma unroll
    for (int it = 0; it < 4; it++) {
        int idx = it * 256 + tid;
        int r = idx >> 4, c = idx & 15;
        int nd = node0 + r;
        if (nd < N_NODES) {
            uint2 vv = *(const uint2*)&Cs[r * 72 + c * 4];
            *(uint2*)&t1[(size_t)nd * HID_F + c * 4] = vv;
        }
    }
}

// ---------------- FUSED agg1+gemm2: h1 lives in LDS only; emits t2s --------------
// Phase A (agg1): 8-lane group = node, lane fl holds feats 8fl..8fl+7 (uint4 gather).
// Phase B (gemm2): MFMA h1s @ Wt2 -> t2s = bf16(dinv * (h1@W2)).
__global__ __launch_bounds__(256) void agg1gemm2_kernel(const unsigned short* __restrict__ t1,
                                                        const int* __restrict__ rowptr,
                                                        const int* __restrict__ col,
                                                        const float* __restrict__ dinv,
                                                        const float* __restrict__ b1,
                                                        const unsigned short* __restrict__ Wt2,
                                                        unsigned short* __restrict__ t2s) {
    __shared__ int lcol[AGG_CAP];
    __shared__ int lrp[65];
    __shared__ float ldv[64];
    __shared__ unsigned short h1s[64 * 72];   // bf16 h1 tile, row stride 72 shorts
    __shared__ unsigned short Cs[64 * 36];    // t2s staging
    int tid = threadIdx.x;
    int node0 = blockIdx.x * 64;
    if (tid < 65) lrp[tid] = rowptr[min(node0 + tid, N_NODES)];
    __syncthreads();
    int s0 = lrp[0];
    int cnt = lrp[64] - s0; if (cnt > AGG_CAP) cnt = AGG_CAP;
    for (int k = tid; k < cnt; k += 256) lcol[k] = col[s0 + k];
    if (tid < 64) {
        int n = node0 + tid;
        ldv[tid] = (n < N_NODES) ? dinv[n] : 0.f;
    }
    __syncthreads();
    int lane = tid & 63, w = tid >> 6;
    int grp = lane >> 3, fl = lane & 7;    // 8 groups/wave, 8 lanes/group (16B each)
    int gg = w * 8 + grp;                  // 0..31
    const uint4* t1q = (const uint4*)t1;   // row stride 8 uint4 (128B)
    float4 bb0 = ((const float4*)b1)[fl * 2];
    float4 bb1 = ((const float4*)b1)[fl * 2 + 1];
#pragma unroll
    for (int rep = 0; rep < 2; rep++) {
        int li = gg + rep * 32;
        int node = node0 + li;
        uint4 pk = make_uint4(0u, 0u, 0u, 0u);
        if (node < N_NODES) {
            int s = lrp[li] - s0;
            int e = lrp[li + 1] - s0; if (e > cnt) e = cnt;
            float a0 = 0.f, a1 = 0.f, a2 = 0.f, a3 = 0.f;
            float a4 = 0.f, a5 = 0.f, a6 = 0.f, a7 = 0.f;
            int p = s;
            for (; p + 3 < e; p += 4) {
                int c0 = lcol[p], c1 = lcol[p + 1], c2 = lcol[p + 2], c3 = lcol[p + 3];
                uint4 u0 = t1q[(size_t)c0 * 8 + fl];
                uint4 u1 = t1q[(size_t)c1 * 8 + fl];
                uint4 u2 = t1q[(size_t)c2 * 8 + fl];
                uint4 u3 = t1q[(size_t)c3 * 8 + fl];
                ACC8(u0); ACC8(u1); ACC8(u2); ACC8(u3);
            }
            for (; p < e; p++) {
                uint4 u = t1q[(size_t)lcol[p] * 8 + fl];
                ACC8(u);
            }
            uint4 us = t1q[(size_t)node * 8 + fl];   // self (already dinv-scaled)
            float di = ldv[li];
            float o0 = fmaxf(di * (a0 + bflo(us.x)) + bb0.x, 0.f);
            float o1 = fmaxf(di * (a1 + bfhi(us.x)) + bb0.y, 0.f);
            float o2 = fmaxf(di * (a2 + bflo(us.y)) + bb0.z, 0.f);
            float o3 = fmaxf(di * (a3 + bfhi(us.y)) + bb0.w, 0.f);
            float o4 = fmaxf(di * (a4 + bflo(us.z)) + bb1.x, 0.f);
            float o5 = fmaxf(di * (a5 + bfhi(us.z)) + bb1.y, 0.f);
            float o6 = fmaxf(di * (a6 + bflo(us.w)) + bb1.z, 0.f);
            float o7 = fmaxf(di * (a7 + bfhi(us.w)) + bb1.w, 0.f);
            pk.x = pack2bf(o0, o1);
            pk.y = pack2bf(o2, o3);
            pk.z = pack2bf(o4, o5);
            pk.w = pack2bf(o6, o7);
        }
        *(uint4*)&h1s[li * 72 + fl * 8] = pk;
    }
    __syncthreads();
    // ---- gemm2 MFMA: K=64 (2 steps), N=32 (2 tiles) ----
    int m = lane & 15, quad = lane >> 4;
    int row = w * 16 + m;
    f32x4 acc0 = {0.f, 0.f, 0.f, 0.f};
    f32x4 acc1 = acc0;
#pragma unroll
    for (int ks = 0; ks < 2; ks++) {
        int kb = ks * 32 + quad * 8;
        bf16x8 a  = *(const bf16x8*)&h1s[row * 72 + kb];
        bf16x8 b0 = *(const bf16x8*)&Wt2[(0 * 16 + m) * HID_F + kb];
        bf16x8 b1v = *(const bf16x8*)&Wt2[(1 * 16 + m) * HID_F + kb];
        acc0 = __builtin_amdgcn_mfma_f32_16x16x32_bf16(a, b0, acc0, 0, 0, 0);
        acc1 = __builtin_amdgcn_mfma_f32_16x16x32_bf16(a, b1v, acc1, 0, 0, 0);
    }
    int rbase = w * 16 + quad * 4;
#pragma unroll
    for (int reg = 0; reg < 4; reg++) {
        int r = rbase + reg;
        float d = ldv[r];
        Cs[r * 36 +  0 + m] = f2bf(acc0[reg] * d);
        Cs[r * 36 + 16 + m] = f2bf(acc1[reg] * d);
    }
    __syncthreads();
#pragma unroll
    for (int it = 0; it < 2; it++) {
        int idx = it * 256 + tid;
        int r = idx >> 3, c = idx & 7;
        int nd = node0 + r;
        if (nd < N_NODES) {
            uint2 vv = *(const uint2*)&Cs[r * 36 + c * 4];
            *(uint2*)&t2s[(size_t)nd * Z_F + c * 4] = vv;
        }
    }
}

// ---------------- FUSED agg2+heads: h2 lives in LDS only; emits out --------------
// Phase A (agg2): 4-lane group = node, lane fo holds feats 8fo..8fo+7 (uint4 gather).
// Phase B (heads): MFMA h2s @ Wth(+bias) -> out [mu|lv].
__global__ __launch_bounds__(256) void agg2heads_kernel(const unsigned short* __restrict__ t2s,
                                                        const int* __restrict__ rowptr,
                                                        const int* __restrict__ col,
                                                        const float* __restrict__ dinv,
                                                        const float* __restrict__ b2,
                                                        const unsigned short* __restrict__ Wth,
                                                        const float* __restrict__ bmu,
                                                        const float* __restrict__ blv,
                                                        float* __restrict__ out) {
    __shared__ int lcol[AGG_CAP];
    __shared__ int lrp[65];
    __shared__ float ldv[64];
    __shared__ unsigned short h2s[64 * 40];   // bf16 h2 tile, row stride 40 shorts
    __shared__ float Cf[64 * 68];             // out staging
    __shared__ float bias[64];
    int tid = threadIdx.x;
    int node0 = blockIdx.x * 64;
    if (tid < 65) lrp[tid] = rowptr[min(node0 + tid, N_NODES)];
    else if (tid >= 96 && tid < 128) bias[tid - 96] = bmu[tid - 96];
    else if (tid >= 128 && tid < 160) bias[tid - 96] = blv[tid - 128];
    __syncthreads();
    int s0 = lrp[0];
    int cnt = lrp[64] - s0; if (cnt > AGG_CAP) cnt = AGG_CAP;
    for (int k = tid; k < cnt; k += 256) lcol[k] = col[s0 + k];
    if (tid < 64) {
        int n = node0 + tid;
        ldv[tid] = (n < N_NODES) ? dinv[n] : 0.f;
    }
    __syncthreads();
    int lane = tid & 63, w = tid >> 6;
    int grp = lane >> 2, fo = lane & 3;    // 16 groups/wave, 4 lanes/group (16B each)
    int li = w * 16 + grp;                 // 0..63, single rep
    const uint4* t2q = (const uint4*)t2s;  // row stride 4 uint4 (64B)
    float4 bb0 = ((const float4*)b2)[fo * 2];
    float4 bb1 = ((const float4*)b2)[fo * 2 + 1];
    {
        int node = node0 + li;
        uint4 pk = make_uint4(0u, 0u, 0u, 0u);
        if (node < N_NODES) {
            int s = lrp[li] - s0;
            int e = lrp[li + 1] - s0; if (e > cnt) e = cnt;
            float a0 = 0.f, a1 = 0.f, a2 = 0.f, a3 = 0.f;
            float a4 = 0.f, a5 = 0.f, a6 = 0.f, a7 = 0.f;
            int p = s;
            for (; p + 3 < e; p += 4) {
                int c0 = lcol[p], c1 = lcol[p + 1], c2 = lcol[p + 2], c3 = lcol[p + 3];
                uint4 u0 = t2q[(size_t)c0 * 4 + fo];
                uint4 u1 = t2q[(size_t)c1 * 4 + fo];
                uint4 u2 = t2q[(size_t)c2 * 4 + fo];
                uint4 u3 = t2q[(size_t)c3 * 4 + fo];
                ACC8(u0); ACC8(u1); ACC8(u2); ACC8(u3);
            }
            for (; p < e; p++) {
                uint4 u = t2q[(size_t)lcol[p] * 4 + fo];
                ACC8(u);
            }
            uint4 us = t2q[(size_t)node * 4 + fo];
            float di = ldv[li];
            float o0 = di * (a0 + bflo(us.x)) + bb0.x;
            float o1 = di * (a1 + bfhi(us.x)) + bb0.y;
            float o2 = di * (a2 + bflo(us.y)) + bb0.z;
            float o3 = di * (a3 + bfhi(us.y)) + bb0.w;
            float o4 = di * (a4 + bflo(us.z)) + bb1.x;
            float o5 = di * (a5 + bfhi(us.z)) + bb1.y;
            float o6 = di * (a6 + bflo(us.w)) + bb1.z;
            float o7 = di * (a7 + bfhi(us.w)) + bb1.w;
            pk.x = pack2bf(o0, o1);
            pk.y = pack2bf(o2, o3);
            pk.z = pack2bf(o4, o5);
            pk.w = pack2bf(o6, o7);
        }
        *(uint4*)&h2s[li * 40 + fo * 8] = pk;
    }
    __syncthreads();
    // ---- heads MFMA: K=32 (1 step), N=64 (4 tiles: mu 0-31, lv 32-63) ----
    int m = lane & 15, quad = lane >> 4;
    int row = w * 16 + m;
    int kb = quad * 8;
    bf16x8 a  = *(const bf16x8*)&h2s[row * 40 + kb];
    bf16x8 b0 = *(const bf16x8*)&Wth[(0 * 16 + m) * Z_F + kb];
    bf16x8 b1 = *(const bf16x8*)&Wth[(1 * 16 + m) * Z_F + kb];
    bf16x8 b2v = *(const bf16x8*)&Wth[(2 * 16 + m) * Z_F + kb];
    bf16x8 b3 = *(const bf16x8*)&Wth[(3 * 16 + m) * Z_F + kb];
    f32x4 acc0 = {0.f, 0.f, 0.f, 0.f};
    f32x4 acc1 = acc0, acc2 = acc0, acc3 = acc0;
    acc0 = __builtin_amdgcn_mfma_f32_16x16x32_bf16(a, b0, acc0, 0, 0, 0);
    acc1 = __builtin_amdgcn_mfma_f32_16x16x32_bf16(a, b1, acc1, 0, 0, 0);
    acc2 = __builtin_amdgcn_mfma_f32_16x16x32_bf16(a, b2v, acc2, 0, 0, 0);
    acc3 = __builtin_amdgcn_mfma_f32_16x16x32_bf16(a, b3, acc3, 0, 0, 0);
    int rbase = w * 16 + quad * 4;
#pragma unroll
    for (int reg = 0; reg < 4; reg++) {
        int r = rbase + reg;
        Cf[r * 68 +  0 + m] = acc0[reg] + bias[ 0 + m];
        Cf[r * 68 + 16 + m] = acc1[reg] + bias[16 + m];
        Cf[r * 68 + 32 + m] = acc2[reg] + bias[32 + m];
        Cf[r * 68 + 48 + m] = acc3[reg] + bias[48 + m];
    }
    __syncthreads();
#pragma unroll
    for (int it = 0; it < 2; it++) {
        int idx = it * 256 + tid;
        int r = idx >> 3, c = idx & 7;
        int nd = node0 + r;
        if (nd < N_NODES) {
            float4 vmu = *(const float4*)&Cf[r * 68 + c * 4];
            float4 vlv = *(const float4*)&Cf[r * 68 + 32 + c * 4];
            *(float4*)&out[(size_t)nd * Z_F + c * 4] = vmu;
            *(float4*)&out[(size_t)N_NODES * Z_F + (size_t)nd * Z_F + c * 4] = vlv;
        }
    }
}

extern "C" void kernel_launch(void* const* d_in, const int* in_sizes, int n_in,
                              void* d_out, int out_size, void* d_ws, size_t ws_size,
                              hipStream_t stream) {
    const float* x   = (const float*)d_in[0];
    const int*   ei  = (const int*)d_in[1];
    const float* W1  = (const float*)d_in[2];
    const float* b1  = (const float*)d_in[3];
    const float* W2  = (const float*)d_in[4];
    const float* b2  = (const float*)d_in[5];
    const float* Wmu = (const float*)d_in[6];
    const float* bmu = (const float*)d_in[7];
    const float* Wlv = (const float*)d_in[8];
    const float* blv = (const float*)d_in[9];
    float* out = (float*)d_out;

    char* ws = (char*)d_ws;
    size_t off = 0;
    auto A = [&](size_t bytes) {
        size_t r = off;
        off += (bytes + 255) & ~(size_t)255;
        return r;
    };
    int*   gcur   = (int*)(ws + A((size_t)NBUK * 4));
    int*   rowptr = (int*)(ws + A((size_t)(N_NODES + 1) * 4));
    float* dinv   = (float*)(ws + A((size_t)N_NODES * 4));
    unsigned short* Wt1 = (unsigned short*)(ws + A((size_t)IN_F * HID_F * 2));
    unsigned short* Wt2 = (unsigned short*)(ws + A((size_t)HID_F * Z_F * 2));
    unsigned short* Wth = (unsigned short*)(ws + A((size_t)Z_F * 64 * 2));
    int*   col        = (int*)(ws + A((size_t)N_EDGES * 4));                    // 6.4 MB
    char*  reg1 = ws + A((size_t)NBUK * BCAP * 4);                              // 9.6 MB: pairs -> t2s
    uint32* pairs = (uint32*)reg1;                // dead after p2g1
    unsigned short* t2s = (unsigned short*)reg1;  // 6.4 MB, written by agg1gemm2
    unsigned short* t1 = (unsigned short*)(ws + A((size_t)N_NODES * HID_F * 2)); // 12.8 MB

    hipMemsetAsync(gcur, 0, (size_t)NBUK * 4, stream);

    phase1_kernel<<<P1_BLOCKS + 1, 512, 0, stream>>>(ei, gcur, pairs,
                                                     W1, W2, Wmu, Wlv, Wt1, Wt2, Wth);
    p2g1_kernel<<<NBUK + G1_BLOCKS, 256, 0, stream>>>(pairs, gcur, rowptr, dinv, col,
                                                      x, Wt1, t1);
    agg1gemm2_kernel<<<G1_BLOCKS, 256, 0, stream>>>(t1, rowptr, col, dinv, b1, Wt2, t2s);
    agg2heads_kernel<<<G1_BLOCKS, 256, 0, stream>>>(t2s, rowptr, col, dinv, b2, Wth, bmu, blv, out);
}

// Round 11
// 207.292 us; speedup vs baseline: 1.2374x; 1.0126x over previous
//
#include <hip/hip_runtime.h>

#define N_NODES 100000
#define N_EDGES 1600000
#define IN_F   128
#define HID_F  64
#define Z_F    32
#define NBUK   782          // ceil(100000/128) buckets of 128 dst nodes
#define BCAP   3072         // bucket capacity (mean 2046, sigma ~45)
#define P1T    4096         // edges per phase1 block (8/thread at 512 threads)
#define P1_BLOCKS ((N_EDGES + P1T - 1) / P1T)   // 391
#define AGG_CAP 1536        // LDS col capacity per 64-node block (mean 1024, max ~1140)
#define G1_BLOCKS ((N_NODES + 63) / 64)         // 1563

typedef unsigned int uint32;
typedef __attribute__((ext_vector_type(8))) short bf16x8;
typedef __attribute__((ext_vector_type(4))) float f32x4;

__device__ __forceinline__ unsigned short f2bf(float f) {
    unsigned u = __float_as_uint(f);
    u = (u + 0x7FFF + ((u >> 16) & 1)) >> 16;   // RNE
    return (unsigned short)u;
}
__device__ __forceinline__ uint32 pack2bf(float lo, float hi) {
    return (uint32)f2bf(lo) | ((uint32)f2bf(hi) << 16);
}
__device__ __forceinline__ float bflo(uint32 u) { return __uint_as_float(u << 16); }
__device__ __forceinline__ float bfhi(uint32 u) { return __uint_as_float(u & 0xFFFF0000u); }

#define ACC8(u) { a0 += bflo(u.x); a1 += bfhi(u.x); a2 += bflo(u.y); a3 += bfhi(u.y); \
                  a4 += bflo(u.z); a5 += bfhi(u.z); a6 += bflo(u.w); a7 += bfhi(u.w); }

// ---------------- phase 1: bucket partition (512 thr for TLP); last blk: weights --
__global__ __launch_bounds__(512) void phase1_kernel(const int* __restrict__ ei,
                                                     int* __restrict__ gcur,
                                                     uint32* __restrict__ pairs,
                                                     const float* __restrict__ W1,
                                                     const float* __restrict__ W2,
                                                     const float* __restrict__ Wmu,
                                                     const float* __restrict__ Wlv,
                                                     unsigned short* __restrict__ Wt1,
                                                     unsigned short* __restrict__ Wt2,
                                                     unsigned short* __restrict__ Wth) {
    if (blockIdx.x == P1_BLOCKS) {   // weight transpose/convert block (no graph dep)
        int t = threadIdx.x;
        for (int i = t; i < IN_F * HID_F; i += 512) {        // Wt1[n][k] = W1[k][n]
            int n = i >> 7, k = i & 127;
            Wt1[i] = f2bf(W1[k * HID_F + n]);
        }
        for (int i = t; i < HID_F * Z_F; i += 512) {         // Wt2[n][k] = W2[k][n]
            int n = i >> 6, k = i & 63;
            Wt2[i] = f2bf(W2[k * Z_F + n]);
        }
        for (int i = t; i < Z_F * 64; i += 512) {            // Wth[n][k]: n<32 mu, else lv
            int n = i >> 5, k = i & 31;
            Wth[i] = f2bf(n < 32 ? Wmu[k * Z_F + n] : Wlv[k * Z_F + (n - 32)]);
        }
        return;
    }
    __shared__ int hist[NBUK];
    __shared__ int lbase[NBUK];
    __shared__ int gbase[NBUK];
    __shared__ int lcur[NBUK];
    __shared__ uint32 stage[P1T];
    __shared__ unsigned short sbid[P1T];
    __shared__ int wsum8[8];
    int tid = threadIdx.x;
    int e0 = blockIdx.x * P1T;
    int ecnt = N_EDGES - e0; if (ecnt > P1T) ecnt = P1T;
    for (int b = tid; b < NBUK; b += 512) { hist[b] = 0; lcur[b] = 0; }
    __syncthreads();
    int myd[8];                       // dst cached in regs: read ei's dst half ONCE
#pragma unroll
    for (int i = 0; i < 8; i++) {
        int k = tid + i * 512;
        myd[i] = (k < ecnt) ? ei[N_EDGES + e0 + k] : -1;
    }
#pragma unroll
    for (int i = 0; i < 8; i++)
        if (myd[i] >= 0) atomicAdd(&hist[myd[i] >> 7], 1);
    __syncthreads();
    int t2 = tid * 2;
    int l0 = 0, l1 = 0, s = 0;
    if (t2 + 0 < NBUK) { l0 = hist[t2 + 0]; s += l0; }
    if (t2 + 1 < NBUK) { l1 = hist[t2 + 1]; s += l1; }
    // wave-shuffle inclusive scan of s across 512 threads (barrier-light)
    int lane = tid & 63, wv = tid >> 6;
    int incl = s;
#pragma unroll
    for (int off = 1; off < 64; off <<= 1) {
        int t = __shfl_up(incl, off);
        if (lane >= off) incl += t;
    }
    if (lane == 63) wsum8[wv] = incl;
    __syncthreads();
    int wbase = 0;
    for (int i = 0; i < wv; i++) wbase += wsum8[i];
    int run = wbase + incl - s;       // exclusive prefix of s
    if (t2 + 0 < NBUK) { lbase[t2 + 0] = run; run += l0; }
    if (t2 + 1 < NBUK) { lbase[t2 + 1] = run; }
    for (int b = tid; b < NBUK; b += 512) {
        int h = hist[b];
        gbase[b] = h ? atomicAdd(&gcur[b], h) : 0;
    }
    __syncthreads();
#pragma unroll
    for (int i = 0; i < 8; i++) {
        int k = tid + i * 512;
        if (k < ecnt) {
            int sN = ei[e0 + k];
            int d  = myd[i];
            int b = d >> 7;
            int slot = lbase[b] + atomicAdd(&lcur[b], 1);
            stage[slot] = (uint32)sN | ((uint32)(d & 127) << 17);
            sbid[slot] = (unsigned short)b;
        }
    }
    __syncthreads();
    for (int k = tid; k < ecnt; k += 512) {
        int b = sbid[k];
        int r = gbase[b] + (k - lbase[b]);
        if (r < BCAP) pairs[(size_t)b * BCAP + r] = stage[k];
    }
}

// ---------------- FUSED phase2 || gemm1 (both depend only on phase1) -------------
// blocks [0,NBUK): per-bucket CSR build (self-computed bucket prefix) + dinv
// blocks [NBUK, NBUK+G1_BLOCKS): gemm1 with SELF-COMPUTED dinv (bucket histogram)
__global__ __launch_bounds__(256) void p2g1_kernel(const uint32* __restrict__ pairs,
                                                   const int* __restrict__ gcur,
                                                   int* __restrict__ rowptr,
                                                   float* __restrict__ dinv,
                                                   int* __restrict__ col,
                                                   const float* __restrict__ x,
                                                   const unsigned short* __restrict__ Wt1,
                                                   unsigned short* __restrict__ t1) {
    int tid = threadIdx.x;
    if (blockIdx.x < NBUK) {
        // ---------------- phase2 body ----------------
        __shared__ int lhist[128];
        __shared__ int lscan[128];
        __shared__ int lcur[128];
        __shared__ int stage[BCAP];
        __shared__ int wsum[4];
        int b = blockIdx.x;
        int cnt_b = gcur[b];
        if (cnt_b > BCAP) cnt_b = BCAP;
        // gbase = exclusive prefix sum of gcur over [0, b) — gcur is 3KB, L2-resident
        int partial = 0;
        for (int i = tid; i < b; i += 256) partial += gcur[i];
#pragma unroll
        for (int off = 32; off > 0; off >>= 1) partial += __shfl_down(partial, off);
        if (tid < 128) { lhist[tid] = 0; lcur[tid] = 0; }
        if ((tid & 63) == 0) wsum[tid >> 6] = partial;
        __syncthreads();
        int gbase = wsum[0] + wsum[1] + wsum[2] + wsum[3];
        int node0 = b << 7;
        int nb = N_NODES - node0;
        if (nb > 128) nb = 128;
        const uint32* pb = pairs + (size_t)b * BCAP;
        for (int k = tid; k < cnt_b; k += 256) atomicAdd(&lhist[pb[k] >> 17], 1);
        __syncthreads();
        // wave-shuffle scan over the 128 counters (tid-waves 0,1; barrier-light)
        int v = (tid < 128) ? lhist[tid] : 0;
        int lane = tid & 63, wv = tid >> 6;
        int incl = v;
#pragma unroll
        for (int off = 1; off < 64; off <<= 1) {
            int t = __shfl_up(incl, off);
            if (lane >= off) incl += t;
        }
        if (wv < 2 && lane == 63) wsum[wv] = incl;   // wave totals (gbase read done)
        __syncthreads();
        if (tid < 128) lscan[tid] = incl - v + (wv ? wsum[0] : 0);  // exclusive
        __syncthreads();
        if (tid < nb) {
            rowptr[node0 + tid] = gbase + lscan[tid];
            dinv[node0 + tid] = rsqrtf((float)(lhist[tid] + 1));
        }
        if (b == NBUK - 1 && tid == 0) rowptr[N_NODES] = N_EDGES;
        for (int k = tid; k < cnt_b; k += 256) {
            uint32 u = pb[k];
            int ld = u >> 17;
            int r = atomicAdd(&lcur[ld], 1);
            stage[lscan[ld] + r] = (int)(u & 0x1FFFF);
        }
        __syncthreads();
        for (int k = tid; k < cnt_b; k += 256) col[gbase + k] = stage[k];
        return;
    }
    // ---------------- gemm1 body (self-computed dinv from pairs histogram) -------
    __shared__ unsigned short Cs[64 * 72];
    __shared__ float dv[64];
    __shared__ int h64[64];
    int g = blockIdx.x - NBUK;
    int node0 = g * 64;
    int bk = node0 >> 7, half = (node0 >> 6) & 1;
    int cnt_b = gcur[bk];
    if (cnt_b > BCAP) cnt_b = BCAP;
    if (tid < 64) h64[tid] = 0;
    __syncthreads();
    const uint32* pb = pairs + (size_t)bk * BCAP;
    for (int k = tid; k < cnt_b; k += 256) {
        int ld = pb[k] >> 17;
        if ((ld >> 6) == half) atomicAdd(&h64[ld & 63], 1);
    }
    __syncthreads();
    if (tid < 64) {
        int n = node0 + tid;
        dv[tid] = (n < N_NODES) ? rsqrtf((float)(h64[tid] + 1)) : 0.f;
    }
    __syncthreads();
    int w = tid >> 6, lane = tid & 63;
    int m = lane & 15, quad = lane >> 4;
    int row = w * 16 + m;
    int node = node0 + row;
    const float* xr = x + (size_t)min(node, N_NODES - 1) * IN_F;
    f32x4 acc0 = {0.f, 0.f, 0.f, 0.f};
    f32x4 acc1 = acc0, acc2 = acc0, acc3 = acc0;
#pragma unroll
    for (int ks = 0; ks < 4; ks++) {
        int kb = ks * 32 + quad * 8;
        float4 f0 = *(const float4*)(xr + kb);
        float4 f1 = *(const float4*)(xr + kb + 4);
        union { bf16x8 v; unsigned short u[8]; } A;
        A.u[0] = f2bf(f0.x); A.u[1] = f2bf(f0.y); A.u[2] = f2bf(f0.z); A.u[3] = f2bf(f0.w);
        A.u[4] = f2bf(f1.x); A.u[5] = f2bf(f1.y); A.u[6] = f2bf(f1.z); A.u[7] = f2bf(f1.w);
        bf16x8 b0 = *(const bf16x8*)&Wt1[(0 * 16 + m) * IN_F + kb];
        bf16x8 b1 = *(const bf16x8*)&Wt1[(1 * 16 + m) * IN_F + kb];
        bf16x8 b2 = *(const bf16x8*)&Wt1[(2 * 16 + m) * IN_F + kb];
        bf16x8 b3 = *(const bf16x8*)&Wt1[(3 * 16 + m) * IN_F + kb];
        acc0 = __builtin_amdgcn_mfma_f32_16x16x32_bf16(A.v, b0, acc0, 0, 0, 0);
        acc1 = __builtin_amdgcn_mfma_f32_16x16x32_bf16(A.v, b1, acc1, 0, 0, 0);
        acc2 = __builtin_amdgcn_mfma_f32_16x16x32_bf16(A.v, b2, acc2, 0, 0, 0);
        acc3 = __builtin_amdgcn_mfma_f32_16x16x32_bf16(A.v, b3, acc3, 0, 0, 0);
    }
    int rbase = w * 16 + quad * 4;
#pragma unroll
    for (int reg = 0; reg < 4; reg++) {
        int r = rbase + reg;
        float d = dv[r];
        Cs[r * 72 +  0 + m] = f2bf(acc0[reg] * d);
        Cs[r * 72 + 16 + m] = f2bf(acc1[reg] * d);
        Cs[r * 72 + 32 + m] = f2bf(acc2[reg] * d);
        Cs[r * 72 + 48 + m] = f2bf(acc3[reg] * d);
    }
    __syncthreads();
#pragma unroll
    for (int it = 0; it < 4; it++) {
        int idx = it * 256 + tid;
        int r = idx >> 4, c = idx & 15;
        int nd = node0 + r;
        if (nd < N_NODES) {
            uint2 vv = *(const uint2*)&Cs[r * 72 + c * 4];
            *(uint2*)&t1[(size_t)nd * HID_F + c * 4] = vv;
        }
    }
}

// ---------------- FUSED agg1+gemm2: LDS-diet (Cs overlays lcol) ------------------
// Phase A (agg1): 8-lane group = node, lane fl holds feats 8fl..8fl+7 (uint4 gather).
// Phase B (gemm2): MFMA h1s @ Wt2 -> t2s = bf16(dinv * (h1@W2)).
// LDS ~15.9KB -> 8 blocks/CU (thread-capped), 32 waves/CU for gather latency-hiding.
__global__ __launch_bounds__(256) void agg1gemm2_kernel(const unsigned short* __restrict__ t1,
                                                        const int* __restrict__ rowptr,
                                                        const int* __restrict__ col,
                                                        const float* __restrict__ dinv,
                                                        const float* __restrict__ b1,
                                                        const unsigned short* __restrict__ Wt2,
                                                        unsigned short* __restrict__ t2s) {
    __shared__ __align__(16) int lcol[AGG_CAP];   // 6144 B; overlaid by Cs (4608 B)
    __shared__ int lrp[65];
    __shared__ float ldv[64];
    __shared__ unsigned short h1s[64 * 72];       // bf16 h1 tile, row stride 72 shorts
    unsigned short* Cs = (unsigned short*)lcol;   // t2s staging, after gather barrier
    int tid = threadIdx.x;
    int node0 = blockIdx.x * 64;
    if (tid < 65) lrp[tid] = rowptr[min(node0 + tid, N_NODES)];
    __syncthreads();
    int s0 = lrp[0];
    int cnt = lrp[64] - s0; if (cnt > AGG_CAP) cnt = AGG_CAP;
    for (int k = tid; k < cnt; k += 256) lcol[k] = col[s0 + k];
    if (tid < 64) {
        int n = node0 + tid;
        ldv[tid] = (n < N_NODES) ? dinv[n] : 0.f;
    }
    __syncthreads();
    int lane = tid & 63, w = tid >> 6;
    int grp = lane >> 3, fl = lane & 7;    // 8 groups/wave, 8 lanes/group (16B each)
    int gg = w * 8 + grp;                  // 0..31
    const uint4* t1q = (const uint4*)t1;   // row stride 8 uint4 (128B)
    float4 bb0 = ((const float4*)b1)[fl * 2];
    float4 bb1 = ((const float4*)b1)[fl * 2 + 1];
#pragma unroll
    for (int rep = 0; rep < 2; rep++) {
        int li = gg + rep * 32;
        int node = node0 + li;
        uint4 pk = make_uint4(0u, 0u, 0u, 0u);
        if (node < N_NODES) {
            int s = lrp[li] - s0;
            int e = lrp[li + 1] - s0; if (e > cnt) e = cnt;
            float a0 = 0.f, a1 = 0.f, a2 = 0.f, a3 = 0.f;
            float a4 = 0.f, a5 = 0.f, a6 = 0.f, a7 = 0.f;
            int p = s;
            for (; p + 3 < e; p += 4) {
                int c0 = lcol[p], c1 = lcol[p + 1], c2 = lcol[p + 2], c3 = lcol[p + 3];
                uint4 u0 = t1q[(size_t)c0 * 8 + fl];
                uint4 u1 = t1q[(size_t)c1 * 8 + fl];
                uint4 u2 = t1q[(size_t)c2 * 8 + fl];
                uint4 u3 = t1q[(size_t)c3 * 8 + fl];
                ACC8(u0); ACC8(u1); ACC8(u2); ACC8(u3);
            }
            for (; p < e; p++) {
                uint4 u = t1q[(size_t)lcol[p] * 8 + fl];
                ACC8(u);
            }
            uint4 us = t1q[(size_t)node * 8 + fl];   // self (already dinv-scaled)
            float di = ldv[li];
            float o0 = fmaxf(di * (a0 + bflo(us.x)) + bb0.x, 0.f);
            float o1 = fmaxf(di * (a1 + bfhi(us.x)) + bb0.y, 0.f);
            float o2 = fmaxf(di * (a2 + bflo(us.y)) + bb0.z, 0.f);
            float o3 = fmaxf(di * (a3 + bfhi(us.y)) + bb0.w, 0.f);
            float o4 = fmaxf(di * (a4 + bflo(us.z)) + bb1.x, 0.f);
            float o5 = fmaxf(di * (a5 + bfhi(us.z)) + bb1.y, 0.f);
            float o6 = fmaxf(di * (a6 + bflo(us.w)) + bb1.z, 0.f);
            float o7 = fmaxf(di * (a7 + bfhi(us.w)) + bb1.w, 0.f);
            pk.x = pack2bf(o0, o1);
            pk.y = pack2bf(o2, o3);
            pk.z = pack2bf(o4, o5);
            pk.w = pack2bf(o6, o7);
        }
        *(uint4*)&h1s[li * 72 + fl * 8] = pk;
    }
    __syncthreads();                       // gather done: lcol reads complete
    // ---- gemm2 MFMA: K=64 (2 steps), N=32 (2 tiles) ----
    int m = lane & 15, quad = lane >> 4;
    int row = w * 16 + m;
    f32x4 acc0 = {0.f, 0.f, 0.f, 0.f};
    f32x4 acc1 = acc0;
#pragma unroll
    for (int ks = 0; ks < 2; ks++) {
        int kb = ks * 32 + quad * 8;
        bf16x8 a  = *(const bf16x8*)&h1s[row * 72 + kb];
        bf16x8 b0 = *(const bf16x8*)&Wt2[(0 * 16 + m) * HID_F + kb];
        bf16x8 b1v = *(const bf16x8*)&Wt2[(1 * 16 + m) * HID_F + kb];
        acc0 = __builtin_amdgcn_mfma_f32_16x16x32_bf16(a, b0, acc0, 0, 0, 0);
        acc1 = __builtin_amdgcn_mfma_f32_16x16x32_bf16(a, b1v, acc1, 0, 0, 0);
    }
    int rbase = w * 16 + quad * 4;
#pragma unroll
    for (int reg = 0; reg < 4; reg++) {
        int r = rbase + reg;
        float d = ldv[r];
        Cs[r * 36 +  0 + m] = f2bf(acc0[reg] * d);
        Cs[r * 36 + 16 + m] = f2bf(acc1[reg] * d);
    }
    __syncthreads();
#pragma unroll
    for (int it = 0; it < 2; it++) {
        int idx = it * 256 + tid;
        int r = idx >> 3, c = idx & 7;
        int nd = node0 + r;
        if (nd < N_NODES) {
            uint2 vv = *(const uint2*)&Cs[r * 36 + c * 4];
            *(uint2*)&t2s[(size_t)nd * Z_F + c * 4] = vv;
        }
    }
}

// ---------------- FUSED agg2+heads: LDS-diet (arena + two-pass out staging) ------
// Phase A (agg2): 4-lane group = node, lane fo holds feats 8fo..8fo+7 (uint4 gather).
// Phase B (heads): MFMA h2s @ Wth(+bias) -> out [mu|lv] via 64x36 f32 staging,
// overlaying the arena after all reads are barriered. LDS ~12KB -> 32 waves/CU.
__global__ __launch_bounds__(256) void agg2heads_kernel(const unsigned short* __restrict__ t2s,
                                                        const int* __restrict__ rowptr,
                                                        const int* __restrict__ col,
                                                        const float* __restrict__ dinv,
                                                        const float* __restrict__ b2,
                                                        const unsigned short* __restrict__ Wth,
                                                        const float* __restrict__ bmu,
                                                        const float* __restrict__ blv,
                                                        float* __restrict__ out) {
    // arena: lcol (AGG_CAP=1536 ints) | h2s (64*40 shorts = 2560 shorts = 1280 ints)
    // total 2816 ints = 11264 B. Cf overlay needs 64*36 f32 = 9216 B <= 11264 B.
    __shared__ __align__(16) int arena[2816];
    __shared__ int lrp[65];
    __shared__ float ldv[64];
    __shared__ float bias[64];
    int* lcol = arena;                             // AGG_CAP ints
    unsigned short* h2s = (unsigned short*)(arena + AGG_CAP);  // 64 x 40 shorts (5120 B)
    float* Cf = (float*)arena;                     // 64 x 36 f32 (9216 B) — overlay
    int tid = threadIdx.x;
    int node0 = blockIdx.x * 64;
    if (tid < 65) lrp[tid] = rowptr[min(node0 + tid, N_NODES)];
    else if (tid >= 96 && tid < 128) bias[tid - 96] = bmu[tid - 96];
    else if (tid >= 128 && tid < 160) bias[tid - 96] = blv[tid - 128];
    __syncthreads();
    int s0 = lrp[0];
    int cnt = lrp[64] - s0; if (cnt > AGG_CAP) cnt = AGG_CAP;
    for (int k = tid; k < cnt; k += 256) lcol[k] = col[s0 + k];
    if (tid < 64) {
        int n = node0 + tid;
        ldv[tid] = (n < N_NODES) ? dinv[n] : 0.f;
    }
    __syncthreads();
    int lane = tid & 63, w = tid >> 6;
    int grp = lane >> 2, fo = lane & 3;    // 16 groups/wave, 4 lanes/group (16B each)
    int li = w * 16 + grp;                 // 0..63, single rep
    const uint4* t2q = (const uint4*)t2s;  // row stride 4 uint4 (64B)
    float4 bb0 = ((const float4*)b2)[fo * 2];
    float4 bb1 = ((const float4*)b2)[fo * 2 + 1];
    {
        int node = node0 + li;
        uint4 pk = make_uint4(0u, 0u, 0u, 0u);
        if (node < N_NODES) {
            int s = lrp[li] - s0;
            int e = lrp[li + 1] - s0; if (e > cnt) e = cnt;
            float a0 = 0.f, a1 = 0.f, a2 = 0.f, a3 = 0.f;
            float a4 = 0.f, a5 = 0.f, a6 = 0.f, a7 = 0.f;
            int p = s;
            for (; p + 3 < e; p += 4) {
                int c0 = lcol[p], c1 = lcol[p + 1], c2 = lcol[p + 2], c3 = lcol[p + 3];
                uint4 u0 = t2q[(size_t)c0 * 4 + fo];
                uint4 u1 = t2q[(size_t)c1 * 4 + fo];
                uint4 u2 = t2q[(size_t)c2 * 4 + fo];
                uint4 u3 = t2q[(size_t)c3 * 4 + fo];
                ACC8(u0); ACC8(u1); ACC8(u2); ACC8(u3);
            }
            for (; p < e; p++) {
                uint4 u = t2q[(size_t)lcol[p] * 4 + fo];
                ACC8(u);
            }
            uint4 us = t2q[(size_t)node * 4 + fo];
            float di = ldv[li];
            float o0 = di * (a0 + bflo(us.x)) + bb0.x;
            float o1 = di * (a1 + bfhi(us.x)) + bb0.y;
            float o2 = di * (a2 + bflo(us.y)) + bb0.z;
            float o3 = di * (a3 + bfhi(us.y)) + bb0.w;
            float o4 = di * (a4 + bflo(us.z)) + bb1.x;
            float o5 = di * (a5 + bfhi(us.z)) + bb1.y;
            float o6 = di * (a6 + bflo(us.w)) + bb1.z;
            float o7 = di * (a7 + bfhi(us.w)) + bb1.w;
            pk.x = pack2bf(o0, o1);
            pk.y = pack2bf(o2, o3);
            pk.z = pack2bf(o4, o5);
            pk.w = pack2bf(o6, o7);
        }
        *(uint4*)&h2s[li * 40 + fo * 8] = pk;
    }
    __syncthreads();
    // ---- heads MFMA: K=32 (1 step), N=64 (4 tiles: mu 0-31, lv 32-63) ----
    int m = lane & 15, quad = lane >> 4;
    int row = w * 16 + m;
    int kb = quad * 8;
    bf16x8 a  = *(const bf16x8*)&h2s[row * 40 + kb];
    bf16x8 b0 = *(const bf16x8*)&Wth[(0 * 16 + m) * Z_F + kb];
    bf16x8 b1 = *(const bf16x8*)&Wth[(1 * 16 + m) * Z_F + kb];
    bf16x8 b2v = *(const bf16x8*)&Wth[(2 * 16 + m) * Z_F + kb];
    bf16x8 b3 = *(const bf16x8*)&Wth[(3 * 16 + m) * Z_F + kb];
    f32x4 acc0 = {0.f, 0.f, 0.f, 0.f};
    f32x4 acc1 = acc0, acc2 = acc0, acc3 = acc0;
    acc0 = __builtin_amdgcn_mfma_f32_16x16x32_bf16(a, b0, acc0, 0, 0, 0);
    acc1 = __builtin_amdgcn_mfma_f32_16x16x32_bf16(a, b1, acc1, 0, 0, 0);
    acc2 = __builtin_amdgcn_mfma_f32_16x16x32_bf16(a, b2v, acc2, 0, 0, 0);
    acc3 = __builtin_amdgcn_mfma_f32_16x16x32_bf16(a, b3, acc3, 0, 0, 0);
    __syncthreads();                 // all h2s/lcol reads complete; Cf may overlay
    int rbase = w * 16 + quad * 4;
    float* outlv = out + (size_t)N_NODES * Z_F;
    // pass 1: mu
#pragma unroll
    for (int reg = 0; reg < 4; reg++) {
        int r = rbase + reg;
        Cf[r * 36 +  0 + m] = acc0[reg] + bias[ 0 + m];
        Cf[r * 36 + 16 + m] = acc1[reg] + bias[16 + m];
    }
    __syncthreads();
#pragma unroll
    for (int it = 0; it < 2; it++) {
        int idx = it * 256 + tid;
        int r = idx >> 3, c = idx & 7;
        int nd = node0 + r;
        if (nd < N_NODES)
            *(float4*)&out[(size_t)nd * Z_F + c * 4] = *(const float4*)&Cf[r * 36 + c * 4];
    }
    __syncthreads();
    // pass 2: lv
#pragma unroll
    for (int reg = 0; reg < 4; reg++) {
        int r = rbase + reg;
        Cf[r * 36 +  0 + m] = acc2[reg] + bias[32 + m];
        Cf[r * 36 + 16 + m] = acc3[reg] + bias[48 + m];
    }
    __syncthreads();
#pragma unroll
    for (int it = 0; it < 2; it++) {
        int idx = it * 256 + tid;
        int r = idx >> 3, c = idx & 7;
        int nd = node0 + r;
        if (nd < N_NODES)
            *(float4*)&outlv[(size_t)nd * Z_F + c * 4] = *(const float4*)&Cf[r * 36 + c * 4];
    }
}

extern "C" void kernel_launch(void* const* d_in, const int* in_sizes, int n_in,
                              void* d_out, int out_size, void* d_ws, size_t ws_size,
                              hipStream_t stream) {
    const float* x   = (const float*)d_in[0];
    const int*   ei  = (const int*)d_in[1];
    const float* W1  = (const float*)d_in[2];
    const float* b1  = (const float*)d_in[3];
    const float* W2  = (const float*)d_in[4];
    const float* b2  = (const float*)d_in[5];
    const float* Wmu = (const float*)d_in[6];
    const float* bmu = (const float*)d_in[7];
    const float* Wlv = (const float*)d_in[8];
    const float* blv = (const float*)d_in[9];
    float* out = (float*)d_out;

    char* ws = (char*)d_ws;
    size_t off = 0;
    auto A = [&](size_t bytes) {
        size_t r = off;
        off += (bytes + 255) & ~(size_t)255;
        return r;
    };
    int*   gcur   = (int*)(ws + A((size_t)NBUK * 4));
    int*   rowptr = (int*)(ws + A((size_t)(N_NODES + 1) * 4));
    float* dinv   = (float*)(ws + A((size_t)N_NODES * 4));
    unsigned short* Wt1 = (unsigned short*)(ws + A((size_t)IN_F * HID_F * 2));
    unsigned short* Wt2 = (unsigned short*)(ws + A((size_t)HID_F * Z_F * 2));
    unsigned short* Wth = (unsigned short*)(ws + A((size_t)Z_F * 64 * 2));
    int*   col        = (int*)(ws + A((size_t)N_EDGES * 4));                    // 6.4 MB
    char*  reg1 = ws + A((size_t)NBUK * BCAP * 4);                              // 9.6 MB: pairs -> t2s
    uint32* pairs = (uint32*)reg1;                // dead after p2g1
    unsigned short* t2s = (unsigned short*)reg1;  // 6.4 MB, written by agg1gemm2
    unsigned short* t1 = (unsigned short*)(ws + A((size_t)N_NODES * HID_F * 2)); // 12.8 MB

    hipMemsetAsync(gcur, 0, (size_t)NBUK * 4, stream);

    phase1_kernel<<<P1_BLOCKS + 1, 512, 0, stream>>>(ei, gcur, pairs,
                                                     W1, W2, Wmu, Wlv, Wt1, Wt2, Wth);
    p2g1_kernel<<<NBUK + G1_BLOCKS, 256, 0, stream>>>(pairs, gcur, rowptr, dinv, col,
                                                      x, Wt1, t1);
    agg1gemm2_kernel<<<G1_BLOCKS, 256, 0, stream>>>(t1, rowptr, col, dinv, b1, Wt2, t2s);
    agg2heads_kernel<<<G1_BLOCKS, 256, 0, stream>>>(t2s, rowptr, col, dinv, b2, Wth, bmu, blv, out);
}